// Round 22
// baseline (122.140 us; speedup 1.0000x reference)
//
#include <hip/hip_runtime.h>
#include <hip/hip_bf16.h>
#include <math.h>

#define NH 12
#define DH 64
#define BB 2
#define NN 2048
#define DM 768

typedef short v8s __attribute__((ext_vector_type(8)));
typedef float v4f __attribute__((ext_vector_type(4)));

__device__ __forceinline__ unsigned short f2bf(float f) {
    union { float f; unsigned u; } x; x.f = f;
    unsigned r = x.u + 0x7fffu + ((x.u >> 16) & 1u);
    return (unsigned short)(r >> 16);
}

__device__ __forceinline__ int cvtpk(float lo, float hi2) {
    int r;
    asm("v_cvt_pk_bf16_f32 %0, %1, %2" : "=v"(r) : "v"(lo), "v"(hi2));
    return r;
}

__device__ __forceinline__ void glds16(const void* g, void* l) {
    __builtin_amdgcn_global_load_lds((const __attribute__((address_space(1))) void*)g,
                                     (__attribute__((address_space(3))) void*)l, 16, 0, 0);
}

// ---- weight transpose casts only (x cast is fused into qkv staging): 576 blocks ----
__global__ __launch_bounds__(256) void cast_w_k(
    const float* __restrict__ w0, const float* __restrict__ w1,
    const float* __restrict__ w2, const float* __restrict__ w3,
    unsigned short* __restrict__ o0, unsigned short* __restrict__ o1,
    unsigned short* __restrict__ o2, unsigned short* __restrict__ o3) {
    __shared__ unsigned short t[64][65];
    int idx = blockIdx.x;
    int m = idx / 144, xt = idx % 144;
    const float* in; unsigned short* out;
    switch (m) {
        case 0: in = w0; out = o0; break;
        case 1: in = w1; out = o1; break;
        case 2: in = w2; out = o2; break;
        default: in = w3; out = o3; break;
    }
    int kt = xt / 12, ct = xt % 12;
    int rr = threadIdx.x >> 4, cc = threadIdx.x & 15;
#pragma unroll
    for (int it = 0; it < 4; it++) {
        int row = kt * 64 + it * 16 + rr;
        int col = ct * 64 + cc * 4;
        float4 v = *(const float4*)(in + row * 768 + col);
        t[it * 16 + rr][cc * 4 + 0] = f2bf(v.x);
        t[it * 16 + rr][cc * 4 + 1] = f2bf(v.y);
        t[it * 16 + rr][cc * 4 + 2] = f2bf(v.z);
        t[it * 16 + rr][cc * 4 + 3] = f2bf(v.w);
    }
    __syncthreads();
#pragma unroll
    for (int it = 0; it < 4; it++) {
        int c_l = it * 16 + rr;
        int k_l = cc * 4;
        ushort4 o;
        o.x = t[k_l + 0][c_l];
        o.y = t[k_l + 1][c_l];
        o.z = t[k_l + 2][c_l];
        o.w = t[k_l + 3][c_l];
        *(ushort4*)(out + (ct * 64 + c_l) * 768 + kt * 64 + k_l) = o;
    }
}

// ---- fused QKV projection; A-panel reg-staged from fp32 x (cast fused); 8 waves ----
// 2-buffer: issue A-loads + B-glds for t+1 before compute(t); cvt+ds_write A after;
// vmcnt(0)+barrier publishes. LDS bytes identical to the verified glds16 layout.
__global__ __launch_bounds__(512) void qkv_gemm_k(
    const float* __restrict__ x,
    const unsigned short* __restrict__ wqT, const unsigned short* __restrict__ wkT,
    const unsigned short* __restrict__ wvT,
    const float* __restrict__ bq, const float* __restrict__ bk, const float* __restrict__ bv,
    unsigned short* __restrict__ q, unsigned short* __restrict__ k, unsigned short* __restrict__ vT) {
    __shared__ unsigned short Abuf[2][128 * 32];
    __shared__ unsigned short Bbuf[2][128 * 32];

    int lin = blockIdx.x;                       // 576 = 8 * 72
    int swz = (lin & 7) * 72 + (lin >> 3);
    int ctile = swz % 18;
    int mtile = swz / 18;
    int mat = ctile / 6;
    int col0 = (ctile % 6) * 128;
    const unsigned short* Bsrc = (mat == 0) ? wqT : ((mat == 1) ? wkT : wvT);
    const float* bias = (mat == 0) ? bq : ((mat == 1) ? bk : bv);

    int tid = threadIdx.x;
    int w = tid >> 6, l = tid & 63;
    int q16 = l & 15, g = l >> 4;
    int wr = w >> 2, wc = w & 3;

    int srow = tid >> 2;
    int ss = tid & 3;
    int c16s = ss ^ ((srow >> 1) & 3);
    const float* ap = x + (mtile * 128 + srow) * 768 + (c16s << 3);
    const unsigned short* bp = Bsrc + (col0 + srow) * 768 + (c16s << 3);

    float4 a0, a1;                              // in-flight A regs (single set; no cross-iter state)
    auto issueA = [&](int tt) {
        a0 = *(const float4*)(ap + tt * 32);
        a1 = *(const float4*)(ap + tt * 32 + 4);
    };
    auto issueB = [&](int tt, int buf) {
        glds16(bp + tt * 32, (char*)&Bbuf[buf][0] + tid * 16);
    };
    auto writeA = [&](int buf) {                // compiler inserts the vmcnt for a0/a1 here
        union { int i[4]; v8s v; } u;
        u.i[0] = cvtpk(a0.x, a0.y); u.i[1] = cvtpk(a0.z, a0.w);
        u.i[2] = cvtpk(a1.x, a1.y); u.i[3] = cvtpk(a1.z, a1.w);
        *(v8s*)((char*)&Abuf[buf][0] + tid * 16) = u.v;
    };

    v4f zero = {0.f, 0.f, 0.f, 0.f};
    v4f acc[4][2];
#pragma unroll
    for (int i = 0; i < 4; i++)
#pragma unroll
        for (int j = 0; j < 2; j++) acc[i][j] = zero;

    issueA(0);
    issueB(0, 0);
    writeA(0);
    asm volatile("s_waitcnt vmcnt(0)" ::: "memory");
    __syncthreads();

    int buf = 0;
#pragma unroll 2
    for (int tt = 0; tt < 24; ++tt) {
        if (tt + 1 < 24) { issueA(tt + 1); issueB(tt + 1, buf ^ 1); }
        const char* Ab = (const char*)&Abuf[buf][0];
        const char* Bb = (const char*)&Bbuf[buf][0];
        v8s af[4], bf[2];
#pragma unroll
        for (int f = 0; f < 4; f++) {
            int arow = wr * 64 + f * 16 + q16;
            af[f] = *(const v8s*)(Ab + arow * 64 + ((g ^ ((arow >> 1) & 3)) << 4));
        }
#pragma unroll
        for (int j = 0; j < 2; j++) {
            int brow = wc * 32 + j * 16 + q16;
            bf[j] = *(const v8s*)(Bb + brow * 64 + ((g ^ ((brow >> 1) & 3)) << 4));
        }
        __builtin_amdgcn_s_setprio(1);
#pragma unroll
        for (int i = 0; i < 4; i++)
#pragma unroll
            for (int j = 0; j < 2; j++)
                acc[i][j] = __builtin_amdgcn_mfma_f32_16x16x32_bf16(af[i], bf[j], acc[i][j], 0, 0, 0);
        __builtin_amdgcn_s_setprio(0);
        if (tt + 1 < 24) writeA(buf ^ 1);
        asm volatile("s_waitcnt vmcnt(0)" ::: "memory");
        __syncthreads();
        buf ^= 1;
    }

    const float QSCL = 0.125f * 1.44269504088896340736f;
#pragma unroll
    for (int i = 0; i < 4; i++)
#pragma unroll
        for (int j = 0; j < 2; j++)
#pragma unroll
            for (int r = 0; r < 4; r++) {
                int gr = mtile * 128 + wr * 64 + i * 16 + 4 * g + r;
                int gcl = col0 + wc * 32 + j * 16 + q16;
                int b = gr / NN, n = gr % NN;
                int h = gcl / DH, d = gcl % DH;
                int bh = b * NH + h;
                float v = acc[i][j][r] + bias[gcl];
                if (mat == 0)      q[(bh * NN + n) * DH + d]  = f2bf(v * QSCL);
                else if (mat == 1) k[(bh * NN + n) * DH + d]  = f2bf(v);
                else               vT[(bh * DH + d) * NN + n] = f2bf(v);
            }
}

// ---- flash attention: R14-exact (8 waves = 4 q-strips x 2 kv-halves; KVBLK=32) ----
__global__ __launch_bounds__(512) void attn_k(
    const unsigned short* __restrict__ q, const unsigned short* __restrict__ k,
    const unsigned short* __restrict__ vT, unsigned short* __restrict__ z) {
    __shared__ __align__(16) char Kb[2][2][4096];     // [half][buf] K tile 32kv x 64d (128B rows)
    __shared__ __align__(16) char Vb[2][2][4096];     // [half][buf] V tile 32 rows x 128B (paired d)
    __shared__ unsigned short plds[8][16][36];        // padded 36 -> conflict-free read/write

    int bh = blockIdx.x % 24;
    int qt = blockIdx.x / 24;
    int b = bh / NH, h = bh % NH;
    int tid = threadIdx.x;
    int w = tid >> 6, l = tid & 63;
    int q16 = l & 15, g = l >> 4;
    int ws = w & 3, hf = w >> 2;

    const unsigned short* qp = q + (size_t)bh * NN * DH;
    const unsigned short* kp = k + (size_t)bh * NN * DH;
    const unsigned short* vp = vT + (size_t)bh * DH * NN;
    int qrow = qt * 64 + ws * 16 + q16;

    v8s qf0 = *(const v8s*)(qp + qrow * DH + 8 * g);
    v8s qf1 = *(const v8s*)(qp + qrow * DH + 32 + 8 * g);

    v8s ones;
#pragma unroll
    for (int i = 0; i < 8; i++) ones[i] = (short)0x3F80;   // bf16 1.0

    int hf_s = tid >> 8;
    int s8 = tid & 255;
    int row_s = s8 >> 3, sl = s8 & 7;
    int kc16 = (sl ^ (row_s & 7)) & 7;
    int vj = sl ^ (row_s & 7);
    int vd = row_s + ((vj >> 2) << 5);
    int vkw = vj & 3;

    auto stage = [&](int t, int buf) {
        int kv0 = hf_s * (NN / 2) + t * 32;
        glds16(kp + (kv0 + row_s) * DH + (kc16 << 3), &Kb[hf_s][buf][s8 * 16]);
        glds16(vp + (size_t)vd * NN + kv0 + vkw * 8, &Vb[hf_s][buf][s8 * 16]);
    };

    v4f zero = {0.f, 0.f, 0.f, 0.f};
    float mrow = -INFINITY;
    v4f o[4];
    v4f osum = zero;
#pragma unroll
    for (int dt = 0; dt < 4; dt++) o[dt] = zero;

    stage(0, 0);
    __syncthreads();

    for (int t = 0; t < 32; ++t) {
        int cur = t & 1;
        if (t + 1 < 32) stage(t + 1, cur ^ 1);

        const char* kb = &Kb[hf][cur][0];
        const char* vb = &Vb[hf][cur][0];

        // ---- QK^T: S^T[32 kv][16 q] ----
        v4f st[2];
#pragma unroll
        for (int ct = 0; ct < 2; ct++) {
            int krow = ct * 16 + q16;
            v8s kf0 = *(const v8s*)(kb + krow * 128 + ((g ^ (krow & 7)) << 4));
            v8s kf1 = *(const v8s*)(kb + krow * 128 + (((4 + g) ^ (krow & 7)) << 4));
            __builtin_amdgcn_s_setprio(1);
            st[ct] = __builtin_amdgcn_mfma_f32_16x16x32_bf16(kf0, qf0, zero, 0, 0, 0);
            st[ct] = __builtin_amdgcn_mfma_f32_16x16x32_bf16(kf1, qf1, st[ct], 0, 0, 0);
            __builtin_amdgcn_s_setprio(0);
        }

        float ma = fmaxf(fmaxf(st[0][0], st[0][1]), st[0][2]);
        float mb = fmaxf(fmaxf(st[0][3], st[1][0]), st[1][1]);
        float vmax = fmaxf(fmaxf(ma, mb), fmaxf(st[1][2], st[1][3]));
        vmax = fmaxf(vmax, __shfl_xor(vmax, 16));
        vmax = fmaxf(vmax, __shfl_xor(vmax, 32));

        if (!__all(vmax <= mrow + 8.f)) {
            float mn = fmaxf(mrow, vmax);
            float sc = exp2f(mrow - mn);
#pragma unroll
            for (int dt = 0; dt < 4; dt++)
#pragma unroll
                for (int r = 0; r < 4; r++) o[dt][r] *= sc;
            osum[0] *= sc;
            mrow = mn;
        }

#pragma unroll
        for (int ct = 0; ct < 2; ct++) {
            float p0 = exp2f(st[ct][0] - mrow);
            float p1 = exp2f(st[ct][1] - mrow);
            float p2 = exp2f(st[ct][2] - mrow);
            float p3 = exp2f(st[ct][3] - mrow);
            union { int i[2]; short4 s; } u;
            u.i[0] = cvtpk(p0, p1);
            u.i[1] = cvtpk(p2, p3);
            *(short4*)(&plds[w][q16][ct * 16 + 4 * g]) = u.s;
        }

        v8s pf0 = *(const v8s*)(&plds[w][q16][8 * g]);

        osum = __builtin_amdgcn_mfma_f32_16x16x32_bf16(ones, pf0, osum, 0, 0, 0);

        // ---- PV: V row = dcol&31, slot = ((dcol>>5)*4+g)^(row&7) ----
        __builtin_amdgcn_s_setprio(1);
#pragma unroll
        for (int dt = 0; dt < 4; dt++) {
            int dcol = dt * 16 + q16;
            int rr = dcol & 31;
            int sl2 = (((dcol >> 5) << 2) + g) ^ (rr & 7);
            v8s vf = *(const v8s*)(vb + rr * 128 + (sl2 << 4));
            o[dt] = __builtin_amdgcn_mfma_f32_16x16x32_bf16(vf, pf0, o[dt], 0, 0, 0);
        }
        __builtin_amdgcn_s_setprio(0);
        __syncthreads();
    }

    // ---- cross-half merge via LDS (K/V buffers dead) ----
    float* po = (float*)&Kb[0][0][0];
    float* pm = (float*)&Vb[0][0][0];
    float* pl = pm + 64;
    int row = ws * 16 + q16;

    if (hf == 1) {
#pragma unroll
        for (int dt = 0; dt < 4; dt++)
#pragma unroll
            for (int r = 0; r < 4; r++)
                po[row * 64 + dt * 16 + 4 * g + r] = o[dt][r];
        if (g == 0) { pm[row] = mrow; pl[row] = osum[0]; }
    }
    __syncthreads();
    if (hf == 0) {
        float m1 = pm[row], l1 = pl[row];
        float ms = fmaxf(mrow, m1);
        float a0 = exp2f(mrow - ms), a1 = exp2f(m1 - ms);
        float inv = 1.f / (osum[0] * a0 + l1 * a1);
        int n = qt * 64 + ws * 16 + q16;
#pragma unroll
        for (int dt = 0; dt < 4; dt++) {
            short4 s4;
            s4.x = (short)f2bf((o[dt][0] * a0 + po[row * 64 + dt * 16 + 4 * g + 0] * a1) * inv);
            s4.y = (short)f2bf((o[dt][1] * a0 + po[row * 64 + dt * 16 + 4 * g + 1] * a1) * inv);
            s4.z = (short)f2bf((o[dt][2] * a0 + po[row * 64 + dt * 16 + 4 * g + 2] * a1) * inv);
            s4.w = (short)f2bf((o[dt][3] * a0 + po[row * 64 + dt * 16 + 4 * g + 3] * a1) * inv);
            *(short4*)(&z[((size_t)(b * NN + n)) * DM + h * DH + dt * 16 + 4 * g]) = s4;
        }
    }
}

// ---- output projection: 64x64 tiles, 4 waves (2x2 of 32x32); 768 blocks; unrolled x3 ----
__global__ __launch_bounds__(256) void out_gemm_k(
    const unsigned short* __restrict__ zb, const unsigned short* __restrict__ woT,
    const float* __restrict__ bo, float* __restrict__ out) {
    __shared__ unsigned short Abuf[3][64 * 32];
    __shared__ unsigned short Bbuf[3][64 * 32];

    int lin = blockIdx.x;                       // 768 = 8 * 96
    int swz = (lin & 7) * 96 + (lin >> 3);
    int mtile = swz / 12;
    int ctile = swz % 12;
    int col0 = ctile * 64;

    int tid = threadIdx.x;
    int w = tid >> 6, l = tid & 63;
    int q16 = l & 15, g = l >> 4;
    int wr = w >> 1, wc = w & 1;

    int srow = tid >> 2;
    int ss = tid & 3;
    int c16s = ss ^ ((srow >> 1) & 3);

    auto stage = [&](int tt, int buf) {
        int k0 = tt * 32;
        glds16(zb + (mtile * 64 + srow) * 768 + k0 + (c16s << 3),
               (char*)&Abuf[buf][0] + tid * 16);
        glds16(woT + (col0 + srow) * 768 + k0 + (c16s << 3),
               (char*)&Bbuf[buf][0] + tid * 16);
    };

    v4f zero = {0.f, 0.f, 0.f, 0.f};
    v4f acc[2][2];
#pragma unroll
    for (int i = 0; i < 2; i++)
#pragma unroll
        for (int j = 0; j < 2; j++) acc[i][j] = zero;

    auto kstep = [&](int tt, int rd, int st) {
        if (tt + 2 < 24) stage(tt + 2, st);
        const char* Ab = (const char*)&Abuf[rd][0];
        const char* Bb = (const char*)&Bbuf[rd][0];
        v8s af[2], bf[2];
#pragma unroll
        for (int f = 0; f < 2; f++) {
            int arow = wr * 32 + f * 16 + q16;
            af[f] = *(const v8s*)(Ab + arow * 64 + ((g ^ ((arow >> 1) & 3)) << 4));
            int brow = wc * 32 + f * 16 + q16;
            bf[f] = *(const v8s*)(Bb + brow * 64 + ((g ^ ((brow >> 1) & 3)) << 4));
        }
        __builtin_amdgcn_s_setprio(1);
#pragma unroll
        for (int i = 0; i < 2; i++)
#pragma unroll
            for (int j = 0; j < 2; j++)
                acc[i][j] = __builtin_amdgcn_mfma_f32_16x16x32_bf16(af[i], bf[j], acc[i][j], 0, 0, 0);
        __builtin_amdgcn_s_setprio(0);
        asm volatile("s_waitcnt vmcnt(2)" ::: "memory");
        __builtin_amdgcn_s_barrier();
        asm volatile("" ::: "memory");
    };

    stage(0, 0);
    stage(1, 1);
    asm volatile("s_waitcnt vmcnt(2)" ::: "memory");
    __builtin_amdgcn_s_barrier();
    asm volatile("" ::: "memory");

#pragma unroll 1
    for (int tt = 0; tt < 24; tt += 3) {
        kstep(tt + 0, 0, 2);
        kstep(tt + 1, 1, 0);
        kstep(tt + 2, 2, 1);
    }

#pragma unroll
    for (int i = 0; i < 2; i++)
#pragma unroll
        for (int j = 0; j < 2; j++)
#pragma unroll
            for (int r = 0; r < 4; r++) {
                int gr = mtile * 64 + wr * 32 + i * 16 + 4 * g + r;
                int gc = col0 + wc * 32 + j * 16 + q16;
                out[gr * 768 + gc] = acc[i][j][r] + bo[gc];
            }
}

extern "C" void kernel_launch(void* const* d_in, const int* in_sizes, int n_in,
                              void* d_out, int out_size, void* d_ws, size_t ws_size,
                              hipStream_t stream) {
    const float* x  = (const float*)d_in[0];
    const float* wq = (const float*)d_in[1];
    const float* bq = (const float*)d_in[2];
    const float* wk = (const float*)d_in[3];
    const float* bk = (const float*)d_in[4];
    const float* wv = (const float*)d_in[5];
    const float* bv = (const float*)d_in[6];
    const float* wo = (const float*)d_in[7];
    const float* bo = (const float*)d_in[8];
    float* out = (float*)d_out;

    const int NX = BB * NN * DM;
    const int NW = 768 * 768;

    unsigned short* wsp = (unsigned short*)d_ws;
    unsigned short* xb  = wsp;                 // unused (x cast fused into qkv)
    unsigned short* wqT = xb + NX;
    unsigned short* wkT = wqT + NW;
    unsigned short* wvT = wkT + NW;
    unsigned short* woT = wvT + NW;
    unsigned short* qb  = woT + NW;
    unsigned short* kb  = qb + NX;
    unsigned short* vTb = kb + NX;
    unsigned short* zb  = vTb + NX;

    cast_w_k<<<576, 256, 0, stream>>>(wq, wk, wv, wo, wqT, wkT, wvT, woT);
    qkv_gemm_k<<<576, 512, 0, stream>>>(x, wqT, wkT, wvT, bq, bk, bv, qb, kb, vTb);
    attn_k<<<BB * NH * (NN / 64), 512, 0, stream>>>(qb, kb, vTb, zb);
    out_gemm_k<<<768, 256, 0, stream>>>(zb, woT, bo, out);
}

// Round 23
// 115.630 us; speedup vs baseline: 1.0563x; 1.0563x over previous
//
#include <hip/hip_runtime.h>
#include <hip/hip_bf16.h>
#include <math.h>

#define NH 12
#define DH 64
#define BB 2
#define NN 2048
#define DM 768

typedef short v8s __attribute__((ext_vector_type(8)));
typedef float v4f __attribute__((ext_vector_type(4)));

__device__ __forceinline__ unsigned short f2bf(float f) {
    union { float f; unsigned u; } x; x.f = f;
    unsigned r = x.u + 0x7fffu + ((x.u >> 16) & 1u);
    return (unsigned short)(r >> 16);
}

__device__ __forceinline__ int cvtpk(float lo, float hi2) {
    int r;
    asm("v_cvt_pk_bf16_f32 %0, %1, %2" : "=v"(r) : "v"(lo), "v"(hi2));
    return r;
}

__device__ __forceinline__ void glds16(const void* g, void* l) {
    __builtin_amdgcn_global_load_lds((const __attribute__((address_space(1))) void*)g,
                                     (__attribute__((address_space(3))) void*)l, 16, 0, 0);
}

// ---- fused casts: blocks [0,1536) cast x fp32->bf16 (8 elems/thread);
//      blocks [1536,2112) transpose weights ----
__global__ __launch_bounds__(256) void cast_fused_k(
    const float* __restrict__ x, unsigned short* __restrict__ xb,
    const float* __restrict__ w0, const float* __restrict__ w1,
    const float* __restrict__ w2, const float* __restrict__ w3,
    unsigned short* __restrict__ o0, unsigned short* __restrict__ o1,
    unsigned short* __restrict__ o2, unsigned short* __restrict__ o3) {
    __shared__ unsigned short t[64][65];
    int bid = blockIdx.x;
    if (bid < 1536) {
        int i = (bid * 256 + threadIdx.x) * 8;
        float4 va = *(const float4*)(x + i);
        float4 vb = *(const float4*)(x + i + 4);
        union { unsigned short s[8]; v8s v; } o;
        o.s[0] = f2bf(va.x); o.s[1] = f2bf(va.y); o.s[2] = f2bf(va.z); o.s[3] = f2bf(va.w);
        o.s[4] = f2bf(vb.x); o.s[5] = f2bf(vb.y); o.s[6] = f2bf(vb.z); o.s[7] = f2bf(vb.w);
        *(v8s*)(xb + i) = o.v;
        return;
    }
    int idx = bid - 1536;
    int m = idx / 144, xt = idx % 144;
    const float* in; unsigned short* out;
    switch (m) {
        case 0: in = w0; out = o0; break;
        case 1: in = w1; out = o1; break;
        case 2: in = w2; out = o2; break;
        default: in = w3; out = o3; break;
    }
    int kt = xt / 12, ct = xt % 12;
    int rr = threadIdx.x >> 4, cc = threadIdx.x & 15;
#pragma unroll
    for (int it = 0; it < 4; it++) {
        int row = kt * 64 + it * 16 + rr;
        int col = ct * 64 + cc * 4;
        float4 v = *(const float4*)(in + row * 768 + col);
        t[it * 16 + rr][cc * 4 + 0] = f2bf(v.x);
        t[it * 16 + rr][cc * 4 + 1] = f2bf(v.y);
        t[it * 16 + rr][cc * 4 + 2] = f2bf(v.z);
        t[it * 16 + rr][cc * 4 + 3] = f2bf(v.w);
    }
    __syncthreads();
#pragma unroll
    for (int it = 0; it < 4; it++) {
        int c_l = it * 16 + rr;
        int k_l = cc * 4;
        ushort4 o;
        o.x = t[k_l + 0][c_l];
        o.y = t[k_l + 1][c_l];
        o.z = t[k_l + 2][c_l];
        o.w = t[k_l + 3][c_l];
        *(ushort4*)(out + (ct * 64 + c_l) * 768 + kt * 64 + k_l) = o;
    }
}

// ---- fused QKV projection as one GEMM over N=2304; 8 waves; XCD-swizzled; unrolled x3 (R19) ----
__global__ __launch_bounds__(512) void qkv_gemm_k(
    const unsigned short* __restrict__ xb,
    const unsigned short* __restrict__ wqT, const unsigned short* __restrict__ wkT,
    const unsigned short* __restrict__ wvT,
    const float* __restrict__ bq, const float* __restrict__ bk, const float* __restrict__ bv,
    unsigned short* __restrict__ q, unsigned short* __restrict__ k, unsigned short* __restrict__ vT) {
    __shared__ unsigned short Abuf[3][128 * 32];
    __shared__ unsigned short Bbuf[3][128 * 32];

    int lin = blockIdx.x;                       // 576 = 8 * 72
    int swz = (lin & 7) * 72 + (lin >> 3);
    int ctile = swz % 18;
    int mtile = swz / 18;
    int mat = ctile / 6;
    int col0 = (ctile % 6) * 128;
    const unsigned short* Bsrc = (mat == 0) ? wqT : ((mat == 1) ? wkT : wvT);
    const float* bias = (mat == 0) ? bq : ((mat == 1) ? bk : bv);

    int tid = threadIdx.x;
    int w = tid >> 6, l = tid & 63;
    int q16 = l & 15, g = l >> 4;
    int wr = w >> 2, wc = w & 3;

    int srow = tid >> 2;
    int ss = tid & 3;
    int c16s = ss ^ ((srow >> 1) & 3);

    auto stage = [&](int tt, int buf) {
        int k0 = tt * 32;
        glds16(xb + (mtile * 128 + srow) * 768 + k0 + (c16s << 3),
               (char*)&Abuf[buf][0] + tid * 16);
        glds16(Bsrc + (col0 + srow) * 768 + k0 + (c16s << 3),
               (char*)&Bbuf[buf][0] + tid * 16);
    };

    v4f zero = {0.f, 0.f, 0.f, 0.f};
    v4f acc[4][2];
#pragma unroll
    for (int i = 0; i < 4; i++)
#pragma unroll
        for (int j = 0; j < 2; j++) acc[i][j] = zero;

    auto kstep = [&](int tt, int rd, int st) {
        if (tt + 2 < 24) stage(tt + 2, st);
        const char* Ab = (const char*)&Abuf[rd][0];
        const char* Bb = (const char*)&Bbuf[rd][0];
        v8s af[4], bf[2];
#pragma unroll
        for (int f = 0; f < 4; f++) {
            int arow = wr * 64 + f * 16 + q16;
            af[f] = *(const v8s*)(Ab + arow * 64 + ((g ^ ((arow >> 1) & 3)) << 4));
        }
#pragma unroll
        for (int j = 0; j < 2; j++) {
            int brow = wc * 32 + j * 16 + q16;
            bf[j] = *(const v8s*)(Bb + brow * 64 + ((g ^ ((brow >> 1) & 3)) << 4));
        }
        __builtin_amdgcn_s_setprio(1);
#pragma unroll
        for (int i = 0; i < 4; i++)
#pragma unroll
            for (int j = 0; j < 2; j++)
                acc[i][j] = __builtin_amdgcn_mfma_f32_16x16x32_bf16(af[i], bf[j], acc[i][j], 0, 0, 0);
        __builtin_amdgcn_s_setprio(0);
        asm volatile("s_waitcnt vmcnt(2)" ::: "memory");
        __builtin_amdgcn_s_barrier();
        asm volatile("" ::: "memory");
    };

    stage(0, 0);
    stage(1, 1);
    asm volatile("s_waitcnt vmcnt(2)" ::: "memory");
    __builtin_amdgcn_s_barrier();
    asm volatile("" ::: "memory");

#pragma unroll 1
    for (int tt = 0; tt < 24; tt += 3) {
        kstep(tt + 0, 0, 2);
        kstep(tt + 1, 1, 0);
        kstep(tt + 2, 2, 1);
    }

    const float QSCL = 0.125f * 1.44269504088896340736f;
#pragma unroll
    for (int i = 0; i < 4; i++)
#pragma unroll
        for (int j = 0; j < 2; j++)
#pragma unroll
            for (int r = 0; r < 4; r++) {
                int gr = mtile * 128 + wr * 64 + i * 16 + 4 * g + r;
                int gcl = col0 + wc * 32 + j * 16 + q16;
                int b = gr / NN, n = gr % NN;
                int h = gcl / DH, d = gcl % DH;
                int bh = b * NH + h;
                float v = acc[i][j][r] + bias[gcl];
                if (mat == 0)      q[(bh * NN + n) * DH + d]  = f2bf(v * QSCL);
                else if (mat == 1) k[(bh * NN + n) * DH + d]  = f2bf(v);
                else               vT[(bh * DH + d) * NN + n] = f2bf(v);
            }
}

// ---- flash attention: R14-exact (8 waves = 4 q-strips x 2 kv-halves; KVBLK=32) ----
__global__ __launch_bounds__(512) void attn_k(
    const unsigned short* __restrict__ q, const unsigned short* __restrict__ k,
    const unsigned short* __restrict__ vT, unsigned short* __restrict__ z) {
    __shared__ __align__(16) char Kb[2][2][4096];     // [half][buf] K tile 32kv x 64d (128B rows)
    __shared__ __align__(16) char Vb[2][2][4096];     // [half][buf] V tile 32 rows x 128B (paired d)
    __shared__ unsigned short plds[8][16][36];        // padded 36 -> conflict-free read/write

    int bh = blockIdx.x % 24;
    int qt = blockIdx.x / 24;
    int b = bh / NH, h = bh % NH;
    int tid = threadIdx.x;
    int w = tid >> 6, l = tid & 63;
    int q16 = l & 15, g = l >> 4;
    int ws = w & 3, hf = w >> 2;

    const unsigned short* qp = q + (size_t)bh * NN * DH;
    const unsigned short* kp = k + (size_t)bh * NN * DH;
    const unsigned short* vp = vT + (size_t)bh * DH * NN;
    int qrow = qt * 64 + ws * 16 + q16;

    v8s qf0 = *(const v8s*)(qp + qrow * DH + 8 * g);
    v8s qf1 = *(const v8s*)(qp + qrow * DH + 32 + 8 * g);

    v8s ones;
#pragma unroll
    for (int i = 0; i < 8; i++) ones[i] = (short)0x3F80;   // bf16 1.0

    int hf_s = tid >> 8;
    int s8 = tid & 255;
    int row_s = s8 >> 3, sl = s8 & 7;
    int kc16 = (sl ^ (row_s & 7)) & 7;
    int vj = sl ^ (row_s & 7);
    int vd = row_s + ((vj >> 2) << 5);
    int vkw = vj & 3;

    auto stage = [&](int t, int buf) {
        int kv0 = hf_s * (NN / 2) + t * 32;
        glds16(kp + (kv0 + row_s) * DH + (kc16 << 3), &Kb[hf_s][buf][s8 * 16]);
        glds16(vp + (size_t)vd * NN + kv0 + vkw * 8, &Vb[hf_s][buf][s8 * 16]);
    };

    v4f zero = {0.f, 0.f, 0.f, 0.f};
    float mrow = -INFINITY;
    v4f o[4];
    v4f osum = zero;
#pragma unroll
    for (int dt = 0; dt < 4; dt++) o[dt] = zero;

    stage(0, 0);
    __syncthreads();

    for (int t = 0; t < 32; ++t) {
        int cur = t & 1;
        if (t + 1 < 32) stage(t + 1, cur ^ 1);

        const char* kb = &Kb[hf][cur][0];
        const char* vb = &Vb[hf][cur][0];

        // ---- QK^T: S^T[32 kv][16 q] ----
        v4f st[2];
#pragma unroll
        for (int ct = 0; ct < 2; ct++) {
            int krow = ct * 16 + q16;
            v8s kf0 = *(const v8s*)(kb + krow * 128 + ((g ^ (krow & 7)) << 4));
            v8s kf1 = *(const v8s*)(kb + krow * 128 + (((4 + g) ^ (krow & 7)) << 4));
            __builtin_amdgcn_s_setprio(1);
            st[ct] = __builtin_amdgcn_mfma_f32_16x16x32_bf16(kf0, qf0, zero, 0, 0, 0);
            st[ct] = __builtin_amdgcn_mfma_f32_16x16x32_bf16(kf1, qf1, st[ct], 0, 0, 0);
            __builtin_amdgcn_s_setprio(0);
        }

        float ma = fmaxf(fmaxf(st[0][0], st[0][1]), st[0][2]);
        float mb = fmaxf(fmaxf(st[0][3], st[1][0]), st[1][1]);
        float vmax = fmaxf(fmaxf(ma, mb), fmaxf(st[1][2], st[1][3]));
        vmax = fmaxf(vmax, __shfl_xor(vmax, 16));
        vmax = fmaxf(vmax, __shfl_xor(vmax, 32));

        if (!__all(vmax <= mrow + 8.f)) {
            float mn = fmaxf(mrow, vmax);
            float sc = exp2f(mrow - mn);
#pragma unroll
            for (int dt = 0; dt < 4; dt++)
#pragma unroll
                for (int r = 0; r < 4; r++) o[dt][r] *= sc;
            osum[0] *= sc;
            mrow = mn;
        }

#pragma unroll
        for (int ct = 0; ct < 2; ct++) {
            float p0 = exp2f(st[ct][0] - mrow);
            float p1 = exp2f(st[ct][1] - mrow);
            float p2 = exp2f(st[ct][2] - mrow);
            float p3 = exp2f(st[ct][3] - mrow);
            union { int i[2]; short4 s; } u;
            u.i[0] = cvtpk(p0, p1);
            u.i[1] = cvtpk(p2, p3);
            *(short4*)(&plds[w][q16][ct * 16 + 4 * g]) = u.s;
        }

        v8s pf0 = *(const v8s*)(&plds[w][q16][8 * g]);

        osum = __builtin_amdgcn_mfma_f32_16x16x32_bf16(ones, pf0, osum, 0, 0, 0);

        // ---- PV: V row = dcol&31, slot = ((dcol>>5)*4+g)^(row&7) ----
        __builtin_amdgcn_s_setprio(1);
#pragma unroll
        for (int dt = 0; dt < 4; dt++) {
            int dcol = dt * 16 + q16;
            int rr = dcol & 31;
            int sl2 = (((dcol >> 5) << 2) + g) ^ (rr & 7);
            v8s vf = *(const v8s*)(vb + rr * 128 + (sl2 << 4));
            o[dt] = __builtin_amdgcn_mfma_f32_16x16x32_bf16(vf, pf0, o[dt], 0, 0, 0);
        }
        __builtin_amdgcn_s_setprio(0);
        __syncthreads();
    }

    // ---- cross-half merge via LDS (K/V buffers dead) ----
    float* po = (float*)&Kb[0][0][0];
    float* pm = (float*)&Vb[0][0][0];
    float* pl = pm + 64;
    int row = ws * 16 + q16;

    if (hf == 1) {
#pragma unroll
        for (int dt = 0; dt < 4; dt++)
#pragma unroll
            for (int r = 0; r < 4; r++)
                po[row * 64 + dt * 16 + 4 * g + r] = o[dt][r];
        if (g == 0) { pm[row] = mrow; pl[row] = osum[0]; }
    }
    __syncthreads();
    if (hf == 0) {
        float m1 = pm[row], l1 = pl[row];
        float ms = fmaxf(mrow, m1);
        float a0 = exp2f(mrow - ms), a1 = exp2f(m1 - ms);
        float inv = 1.f / (osum[0] * a0 + l1 * a1);
        int n = qt * 64 + ws * 16 + q16;
#pragma unroll
        for (int dt = 0; dt < 4; dt++) {
            short4 s4;
            s4.x = (short)f2bf((o[dt][0] * a0 + po[row * 64 + dt * 16 + 4 * g + 0] * a1) * inv);
            s4.y = (short)f2bf((o[dt][1] * a0 + po[row * 64 + dt * 16 + 4 * g + 1] * a1) * inv);
            s4.z = (short)f2bf((o[dt][2] * a0 + po[row * 64 + dt * 16 + 4 * g + 2] * a1) * inv);
            s4.w = (short)f2bf((o[dt][3] * a0 + po[row * 64 + dt * 16 + 4 * g + 3] * a1) * inv);
            *(short4*)(&z[((size_t)(b * NN + n)) * DM + h * DH + dt * 16 + 4 * g]) = s4;
        }
    }
}

// ---- output projection: 64x64 tiles, 4 waves (2x2 of 32x32); 768 blocks; unrolled x3 ----
__global__ __launch_bounds__(256) void out_gemm_k(
    const unsigned short* __restrict__ zb, const unsigned short* __restrict__ woT,
    const float* __restrict__ bo, float* __restrict__ out) {
    __shared__ unsigned short Abuf[3][64 * 32];
    __shared__ unsigned short Bbuf[3][64 * 32];

    int lin = blockIdx.x;                       // 768 = 8 * 96
    int swz = (lin & 7) * 96 + (lin >> 3);
    int mtile = swz / 12;
    int ctile = swz % 12;
    int col0 = ctile * 64;

    int tid = threadIdx.x;
    int w = tid >> 6, l = tid & 63;
    int q16 = l & 15, g = l >> 4;
    int wr = w >> 1, wc = w & 1;

    int srow = tid >> 2;
    int ss = tid & 3;
    int c16s = ss ^ ((srow >> 1) & 3);

    auto stage = [&](int tt, int buf) {
        int k0 = tt * 32;
        glds16(zb + (mtile * 64 + srow) * 768 + k0 + (c16s << 3),
               (char*)&Abuf[buf][0] + tid * 16);
        glds16(woT + (col0 + srow) * 768 + k0 + (c16s << 3),
               (char*)&Bbuf[buf][0] + tid * 16);
    };

    v4f zero = {0.f, 0.f, 0.f, 0.f};
    v4f acc[2][2];
#pragma unroll
    for (int i = 0; i < 2; i++)
#pragma unroll
        for (int j = 0; j < 2; j++) acc[i][j] = zero;

    auto kstep = [&](int tt, int rd, int st) {
        if (tt + 2 < 24) stage(tt + 2, st);
        const char* Ab = (const char*)&Abuf[rd][0];
        const char* Bb = (const char*)&Bbuf[rd][0];
        v8s af[2], bf[2];
#pragma unroll
        for (int f = 0; f < 2; f++) {
            int arow = wr * 32 + f * 16 + q16;
            af[f] = *(const v8s*)(Ab + arow * 64 + ((g ^ ((arow >> 1) & 3)) << 4));
            int brow = wc * 32 + f * 16 + q16;
            bf[f] = *(const v8s*)(Bb + brow * 64 + ((g ^ ((brow >> 1) & 3)) << 4));
        }
        __builtin_amdgcn_s_setprio(1);
#pragma unroll
        for (int i = 0; i < 2; i++)
#pragma unroll
            for (int j = 0; j < 2; j++)
                acc[i][j] = __builtin_amdgcn_mfma_f32_16x16x32_bf16(af[i], bf[j], acc[i][j], 0, 0, 0);
        __builtin_amdgcn_s_setprio(0);
        asm volatile("s_waitcnt vmcnt(2)" ::: "memory");
        __builtin_amdgcn_s_barrier();
        asm volatile("" ::: "memory");
    };

    stage(0, 0);
    stage(1, 1);
    asm volatile("s_waitcnt vmcnt(2)" ::: "memory");
    __builtin_amdgcn_s_barrier();
    asm volatile("" ::: "memory");

#pragma unroll 1
    for (int tt = 0; tt < 24; tt += 3) {
        kstep(tt + 0, 0, 2);
        kstep(tt + 1, 1, 0);
        kstep(tt + 2, 2, 1);
    }

#pragma unroll
    for (int i = 0; i < 2; i++)
#pragma unroll
        for (int j = 0; j < 2; j++)
#pragma unroll
            for (int r = 0; r < 4; r++) {
                int gr = mtile * 64 + wr * 32 + i * 16 + 4 * g + r;
                int gc = col0 + wc * 32 + j * 16 + q16;
                out[gr * 768 + gc] = acc[i][j][r] + bo[gc];
            }
}

extern "C" void kernel_launch(void* const* d_in, const int* in_sizes, int n_in,
                              void* d_out, int out_size, void* d_ws, size_t ws_size,
                              hipStream_t stream) {
    const float* x  = (const float*)d_in[0];
    const float* wq = (const float*)d_in[1];
    const float* bq = (const float*)d_in[2];
    const float* wk = (const float*)d_in[3];
    const float* bk = (const float*)d_in[4];
    const float* wv = (const float*)d_in[5];
    const float* bv = (const float*)d_in[6];
    const float* wo = (const float*)d_in[7];
    const float* bo = (const float*)d_in[8];
    float* out = (float*)d_out;

    const int NX = BB * NN * DM;
    const int NW = 768 * 768;

    unsigned short* wsp = (unsigned short*)d_ws;
    unsigned short* xb  = wsp;
    unsigned short* wqT = xb + NX;
    unsigned short* wkT = wqT + NW;
    unsigned short* wvT = wkT + NW;
    unsigned short* woT = wvT + NW;
    unsigned short* qb  = woT + NW;
    unsigned short* kb  = qb + NX;
    unsigned short* vTb = kb + NX;
    unsigned short* zb  = vTb + NX;

    cast_fused_k<<<2112, 256, 0, stream>>>(x, xb, wq, wk, wv, wo, wqT, wkT, wvT, woT);
    qkv_gemm_k<<<576, 512, 0, stream>>>(xb, wqT, wkT, wvT, bq, bk, bv, qb, kb, vTb);
    attn_k<<<BB * NH * (NN / 64), 512, 0, stream>>>(qb, kb, vTb, zb);
    out_gemm_k<<<768, 256, 0, stream>>>(zb, woT, bo, out);
}